// Round 8
// baseline (490.902 us; speedup 1.0000x reference)
//
#include <hip/hip_runtime.h>
#include <math.h>

#define T_TOTAL 16384
#define HDIM    2048
#define NEXP    64

// ---------------------------------------------------------------------------
// GEMM:  partial[ks][e][t] = sum_{k in slice ks} x[t][k] * w[e][k]
// Block: 256 threads = 4 waves, 256 tokens x 64 experts.
//   wave -> 16 experts, W read from LDS via uniform-address ds_read_b128
//           BROADCAST (conflict-free, no scalar pipe, no s_load/ds lgkm mix)
//   lane -> 4 consecutive tokens (lane-linear ds_read_b128 from Xs)
// 16 named float4 accumulators (no dynamic indexing -> no spill).
// Stores: one coalesced b128 per expert.
// ---------------------------------------------------------------------------
template<int KS>
__global__ __launch_bounds__(256, 4)
void router_gemm_kernel(const float* __restrict__ x,
                        const float* __restrict__ w,
                        float* __restrict__ partial)
{
    constexpr int KSLICE = HDIM / KS;   // 128 for KS=16
    constexpr int BK     = 16;
    constexpr int XS_ST  = 260;         // 16B-aligned rows; 2-way staging = free

    __shared__ __align__(16) float Xs[BK][XS_ST];
    __shared__ __align__(16) float Ws[NEXP][BK];   // [expert][k] rows 64B

    const int tid  = threadIdx.x;
    const int lane = tid & 63;
    const int tb   = blockIdx.x & 63;
    const int ks   = blockIdx.x >> 6;
    const int t0   = tb * 256;
    const int k0   = ks * KSLICE;
    const int e0   = (tid >> 6) * 16;    // this wave's 16 experts
    const int l4   = lane * 4;           // this lane's 4 tokens

    const int kq = tid & 3;              // staging k-quad
    const int rr = tid >> 2;             // staging row 0..63
    const int we = tid >> 2;             // W staging expert 0..63

    float4 A0 = {0,0,0,0}, A1 = {0,0,0,0}, A2 = {0,0,0,0}, A3 = {0,0,0,0};
    float4 A4 = {0,0,0,0}, A5 = {0,0,0,0}, A6 = {0,0,0,0}, A7 = {0,0,0,0};
    float4 A8 = {0,0,0,0}, A9 = {0,0,0,0}, A10 = {0,0,0,0}, A11 = {0,0,0,0};
    float4 A12 = {0,0,0,0}, A13 = {0,0,0,0}, A14 = {0,0,0,0}, A15 = {0,0,0,0};

// one expert j over a 4-k group: broadcast b128 W read + 16 fmaf
#define EXPQ(j)                                                             \
    {                                                                       \
        const float4 wv = *(const float4*)&Ws[e0 + (j)][kk];                \
        A##j.x = fmaf(xr0.x, wv.x, A##j.x);                                 \
        A##j.y = fmaf(xr0.y, wv.x, A##j.y);                                 \
        A##j.z = fmaf(xr0.z, wv.x, A##j.z);                                 \
        A##j.w = fmaf(xr0.w, wv.x, A##j.w);                                 \
        A##j.x = fmaf(xr1.x, wv.y, A##j.x);                                 \
        A##j.y = fmaf(xr1.y, wv.y, A##j.y);                                 \
        A##j.z = fmaf(xr1.z, wv.y, A##j.z);                                 \
        A##j.w = fmaf(xr1.w, wv.y, A##j.w);                                 \
        A##j.x = fmaf(xr2.x, wv.z, A##j.x);                                 \
        A##j.y = fmaf(xr2.y, wv.z, A##j.y);                                 \
        A##j.z = fmaf(xr2.z, wv.z, A##j.z);                                 \
        A##j.w = fmaf(xr2.w, wv.z, A##j.w);                                 \
        A##j.x = fmaf(xr3.x, wv.w, A##j.x);                                 \
        A##j.y = fmaf(xr3.y, wv.w, A##j.y);                                 \
        A##j.z = fmaf(xr3.z, wv.w, A##j.z);                                 \
        A##j.w = fmaf(xr3.w, wv.w, A##j.w);                                 \
    }

#pragma unroll 1
    for (int kc = 0; kc < KSLICE; kc += BK) {
        __syncthreads();

        // stage X: 256 tokens x 16 k, transposed -> [k][token] (2-way = free)
        {
            const float* xg = x + (size_t)t0 * HDIM + (k0 + kc) + kq * 4;
#pragma unroll
            for (int p = 0; p < 4; ++p) {
                const int r = p * 64 + rr;
                const float4 v = *(const float4*)(xg + (size_t)r * HDIM);
                Xs[kq * 4 + 0][r] = v.x;
                Xs[kq * 4 + 1][r] = v.y;
                Xs[kq * 4 + 2][r] = v.z;
                Xs[kq * 4 + 3][r] = v.w;
            }
        }
        // stage W: 64 experts x 16 k -> [e][k], contiguous b128 writes
        {
            const float4 v = *(const float4*)(w + (size_t)we * HDIM + (k0 + kc) + kq * 4);
            *(float4*)&Ws[we][kq * 4] = v;
        }
        __syncthreads();

#pragma unroll
        for (int kk = 0; kk < BK; kk += 4) {
            const float4 xr0 = *(const float4*)&Xs[kk + 0][l4];
            const float4 xr1 = *(const float4*)&Xs[kk + 1][l4];
            const float4 xr2 = *(const float4*)&Xs[kk + 2][l4];
            const float4 xr3 = *(const float4*)&Xs[kk + 3][l4];
            EXPQ(0)  EXPQ(1)  EXPQ(2)  EXPQ(3)
            EXPQ(4)  EXPQ(5)  EXPQ(6)  EXPQ(7)
            EXPQ(8)  EXPQ(9)  EXPQ(10) EXPQ(11)
            EXPQ(12) EXPQ(13) EXPQ(14) EXPQ(15)
        }
    }
#undef EXPQ

    float* pb = partial + ((size_t)ks * NEXP + e0) * T_TOTAL + t0 + l4;
#define ST(j) *(float4*)(pb + (size_t)(j) * T_TOTAL) = A##j;
    ST(0)  ST(1)  ST(2)  ST(3)  ST(4)  ST(5)  ST(6)  ST(7)
    ST(8)  ST(9)  ST(10) ST(11) ST(12) ST(13) ST(14) ST(15)
#undef ST
}

// ---------------------------------------------------------------------------
// Fused reduce + sigmoid + top-8.  Block = 1024 threads (16 waves) / 64
// tokens -> 16 waves/CU (R7 had 4: latency-bound).
// Phase 1: wave -> 4 experts, lane -> token: coalesced 256 B reads, KS loads
//          unrolled & independent; sigmoid -> Ls[t][e] (stride 65, 2-way).
// Phase 2: wave -> 4 tokens, shuffle argmax top-8, lower-index tie-break,
//          renorm * 2.5.
// ---------------------------------------------------------------------------
template<int KS>
__global__ __launch_bounds__(1024)
void router_topk_kernel(const float* __restrict__ partial,
                        const float* __restrict__ bias,
                        float* __restrict__ out_scores,
                        float* __restrict__ out_idx)
{
    __shared__ float Ls[64][65];

    const int tid  = threadIdx.x;
    const int lane = tid & 63;
    const int wv   = tid >> 6;           // 0..15
    const int t0   = blockIdx.x * 64;

    // Phase 1: 16 waves x 4 experts
#pragma unroll
    for (int it = 0; it < 4; ++it) {
        const int e = it * 16 + wv;
        const float* p = partial + (size_t)e * T_TOTAL + t0 + lane;
        float lg = 0.0f;
#pragma unroll
        for (int s = 0; s < KS; ++s)
            lg += p[(size_t)s * NEXP * T_TOTAL];
        Ls[lane][e] = 1.0f / (1.0f + expf(-lg));
    }
    __syncthreads();

    const float bv = bias[lane];

    // Phase 2: 16 waves x 4 tokens
#pragma unroll 1
    for (int tt = 0; tt < 4; ++tt) {
        const int trow  = wv * 4 + tt;
        const int token = t0 + trow;
        const float score = Ls[trow][lane];
        float key = score + bv;

        float myscore = 0.0f;
        int   myidx   = 0;
        float denom   = 0.0f;
#pragma unroll
        for (int r = 0; r < 8; ++r) {
            float bk = key;
            int   bi = lane;
#pragma unroll
            for (int off = 32; off > 0; off >>= 1) {
                const float ok = __shfl_xor(bk, off);
                const int   oi = __shfl_xor(bi, off);
                if (ok > bk || (ok == bk && oi < bi)) { bk = ok; bi = oi; }
            }
            const float wsc = __shfl(score, bi);
            denom += wsc;
            if (lane == r)  { myscore = wsc; myidx = bi; }
            if (lane == bi) key = -__builtin_inff();
        }
        const float f = 2.5f / (denom + 1e-20f);
        if (lane < 8) {
            out_scores[(size_t)token * 8 + lane] = myscore * f;
            out_idx  [(size_t)token * 8 + lane] = (float)myidx;
        }
    }
}

// ---------------------------------------------------------------------------
extern "C" void kernel_launch(void* const* d_in, const int* in_sizes, int n_in,
                              void* d_out, int out_size, void* d_ws, size_t ws_size,
                              hipStream_t stream)
{
    const float* x    = (const float*)d_in[0];   // [4,4096,2048] f32
    const float* bias = (const float*)d_in[1];   // [64] f32
    const float* w    = (const float*)d_in[2];   // [64,2048] f32

    float* out     = (float*)d_out;
    float* partial = (float*)d_ws;

    const size_t bytesPerSlice = (size_t)T_TOTAL * NEXP * 4;   // 4 MiB

    if (ws_size >= 16 * bytesPerSlice) {
        router_gemm_kernel<16><<<dim3(64 * 16), dim3(256), 0, stream>>>(x, w, partial);
        router_topk_kernel<16><<<dim3(T_TOTAL / 64), dim3(1024), 0, stream>>>(
            partial, bias, out, out + (size_t)T_TOTAL * 8);
    } else {
        router_gemm_kernel<4><<<dim3(64 * 4), dim3(256), 0, stream>>>(x, w, partial);
        router_topk_kernel<4><<<dim3(T_TOTAL / 64), dim3(1024), 0, stream>>>(
            partial, bias, out, out + (size_t)T_TOTAL * 8);
    }
}

// Round 9
// 305.637 us; speedup vs baseline: 1.6062x; 1.6062x over previous
//
#include <hip/hip_runtime.h>
#include <math.h>

#define T_TOTAL 16384
#define HDIM    2048
#define NEXP    64

// ---------------------------------------------------------------------------
// GEMM:  partial[ks][e][t] = sum_{k in slice ks} x[t][k] * w[e][k]
// Block: 256 threads = 4 waves, 256 tokens x 64 experts.
//   wave -> 16 experts, W from LDS via uniform-address (broadcast)
//           ds_read_b128: conflict-free, homogeneous lgkm stream (no K$-
//           missing s_load mix -- the R7 defect).
//   lane -> 4 consecutive tokens (lane-linear ds_read_b128 from Xs).
// 16 named float4 accumulators (no dynamic indexing).
// __launch_bounds__(256,3): VGPR cap 170 (NOT 128 -- R8's cap-128 spilled
// the accs to scratch: WRITE 767 MB). Need ~111 VGPRs -> headroom.
// W staging addr = 16*lane bytes -> contiguous b128 writes, conflict-free.
// ---------------------------------------------------------------------------
template<int KS>
__global__ __launch_bounds__(256, 3)
void router_gemm_kernel(const float* __restrict__ x,
                        const float* __restrict__ w,
                        float* __restrict__ partial)
{
    constexpr int KSLICE = HDIM / KS;   // 128 for KS=16
    constexpr int BK     = 16;
    constexpr int XS_ST  = 260;         // 16B-aligned rows; 2-way staging = free

    __shared__ __align__(16) float Xs[BK][XS_ST];
    __shared__ __align__(16) float Ws[NEXP][BK];   // [expert][k], 64 B rows

    const int tid  = threadIdx.x;
    const int lane = tid & 63;
    const int wid  = __builtin_amdgcn_readfirstlane(tid >> 6);
    const int tb   = blockIdx.x & 63;
    const int ks   = blockIdx.x >> 6;
    const int t0   = tb * 256;
    const int k0   = ks * KSLICE;
    const int e0   = wid * 16;           // this wave's 16 experts (uniform)
    const int l4   = lane * 4;           // this lane's 4 tokens

    const int kq = tid & 3;              // staging k-quad
    const int rr = tid >> 2;             // staging row 0..63

    float4 A0 = {0,0,0,0}, A1 = {0,0,0,0}, A2 = {0,0,0,0}, A3 = {0,0,0,0};
    float4 A4 = {0,0,0,0}, A5 = {0,0,0,0}, A6 = {0,0,0,0}, A7 = {0,0,0,0};
    float4 A8 = {0,0,0,0}, A9 = {0,0,0,0}, A10 = {0,0,0,0}, A11 = {0,0,0,0};
    float4 A12 = {0,0,0,0}, A13 = {0,0,0,0}, A14 = {0,0,0,0}, A15 = {0,0,0,0};

// one expert j over a 4-k group: broadcast b128 W read + 16 fmaf
// (load used immediately -> short live range)
#define EXPQ(j)                                                             \
    {                                                                       \
        const float4 wv = *(const float4*)&Ws[e0 + (j)][kk];                \
        A##j.x = fmaf(xr0.x, wv.x, A##j.x);                                 \
        A##j.y = fmaf(xr0.y, wv.x, A##j.y);                                 \
        A##j.z = fmaf(xr0.z, wv.x, A##j.z);                                 \
        A##j.w = fmaf(xr0.w, wv.x, A##j.w);                                 \
        A##j.x = fmaf(xr1.x, wv.y, A##j.x);                                 \
        A##j.y = fmaf(xr1.y, wv.y, A##j.y);                                 \
        A##j.z = fmaf(xr1.z, wv.y, A##j.z);                                 \
        A##j.w = fmaf(xr1.w, wv.y, A##j.w);                                 \
        A##j.x = fmaf(xr2.x, wv.z, A##j.x);                                 \
        A##j.y = fmaf(xr2.y, wv.z, A##j.y);                                 \
        A##j.z = fmaf(xr2.z, wv.z, A##j.z);                                 \
        A##j.w = fmaf(xr2.w, wv.z, A##j.w);                                 \
        A##j.x = fmaf(xr3.x, wv.w, A##j.x);                                 \
        A##j.y = fmaf(xr3.y, wv.w, A##j.y);                                 \
        A##j.z = fmaf(xr3.z, wv.w, A##j.z);                                 \
        A##j.w = fmaf(xr3.w, wv.w, A##j.w);                                 \
    }

#pragma unroll 1
    for (int kc = 0; kc < KSLICE; kc += BK) {
        __syncthreads();

        // stage X: 256 tokens x 16 k, transposed -> [k][token] (2-way = free)
        {
            const float* xg = x + (size_t)t0 * HDIM + (k0 + kc) + kq * 4;
#pragma unroll
            for (int p = 0; p < 4; ++p) {
                const int r = p * 64 + rr;
                const float4 v = *(const float4*)(xg + (size_t)r * HDIM);
                Xs[kq * 4 + 0][r] = v.x;
                Xs[kq * 4 + 1][r] = v.y;
                Xs[kq * 4 + 2][r] = v.z;
                Xs[kq * 4 + 3][r] = v.w;
            }
        }
        // stage W: 64 experts x 16 k -> [e][k]; byte addr = 16*lane ->
        // contiguous, conflict-free b128 writes
        {
            const int we = tid >> 2;
            const float4 v = *(const float4*)(w + (size_t)we * HDIM + (k0 + kc) + kq * 4);
            *(float4*)&Ws[we][kq * 4] = v;
        }
        __syncthreads();

#pragma unroll
        for (int kk = 0; kk < BK; kk += 4) {
            const float4 xr0 = *(const float4*)&Xs[kk + 0][l4];
            const float4 xr1 = *(const float4*)&Xs[kk + 1][l4];
            const float4 xr2 = *(const float4*)&Xs[kk + 2][l4];
            const float4 xr3 = *(const float4*)&Xs[kk + 3][l4];
            EXPQ(0)  EXPQ(1)  EXPQ(2)  EXPQ(3)
            EXPQ(4)  EXPQ(5)  EXPQ(6)  EXPQ(7)
            EXPQ(8)  EXPQ(9)  EXPQ(10) EXPQ(11)
            EXPQ(12) EXPQ(13) EXPQ(14) EXPQ(15)
        }
    }
#undef EXPQ

    float* pb = partial + ((size_t)ks * NEXP + e0) * T_TOTAL + t0 + l4;
#define ST(j) *(float4*)(pb + (size_t)(j) * T_TOTAL) = A##j;
    ST(0)  ST(1)  ST(2)  ST(3)  ST(4)  ST(5)  ST(6)  ST(7)
    ST(8)  ST(9)  ST(10) ST(11) ST(12) ST(13) ST(14) ST(15)
#undef ST
}

// ---------------------------------------------------------------------------
// Fused reduce + sigmoid + top-8 (unchanged from R8: measured ~19 us).
// Block = 1024 threads (16 waves) / 64 tokens -> 16 waves/CU.
// ---------------------------------------------------------------------------
template<int KS>
__global__ __launch_bounds__(1024)
void router_topk_kernel(const float* __restrict__ partial,
                        const float* __restrict__ bias,
                        float* __restrict__ out_scores,
                        float* __restrict__ out_idx)
{
    __shared__ float Ls[64][65];

    const int tid  = threadIdx.x;
    const int lane = tid & 63;
    const int wv   = tid >> 6;           // 0..15
    const int t0   = blockIdx.x * 64;

    // Phase 1: 16 waves x 4 experts, lane = token (coalesced 256 B reads)
#pragma unroll
    for (int it = 0; it < 4; ++it) {
        const int e = it * 16 + wv;
        const float* p = partial + (size_t)e * T_TOTAL + t0 + lane;
        float lg = 0.0f;
#pragma unroll
        for (int s = 0; s < KS; ++s)
            lg += p[(size_t)s * NEXP * T_TOTAL];
        Ls[lane][e] = 1.0f / (1.0f + expf(-lg));
    }
    __syncthreads();

    const float bv = bias[lane];

    // Phase 2: wave -> 4 tokens, shuffle argmax top-8, lower-idx tie-break
#pragma unroll 1
    for (int tt = 0; tt < 4; ++tt) {
        const int trow  = wv * 4 + tt;
        const int token = t0 + trow;
        const float score = Ls[trow][lane];
        float key = score + bv;

        float myscore = 0.0f;
        int   myidx   = 0;
        float denom   = 0.0f;
#pragma unroll
        for (int r = 0; r < 8; ++r) {
            float bk = key;
            int   bi = lane;
#pragma unroll
            for (int off = 32; off > 0; off >>= 1) {
                const float ok = __shfl_xor(bk, off);
                const int   oi = __shfl_xor(bi, off);
                if (ok > bk || (ok == bk && oi < bi)) { bk = ok; bi = oi; }
            }
            const float wsc = __shfl(score, bi);
            denom += wsc;
            if (lane == r)  { myscore = wsc; myidx = bi; }
            if (lane == bi) key = -__builtin_inff();
        }
        const float f = 2.5f / (denom + 1e-20f);
        if (lane < 8) {
            out_scores[(size_t)token * 8 + lane] = myscore * f;
            out_idx  [(size_t)token * 8 + lane] = (float)myidx;
        }
    }
}

// ---------------------------------------------------------------------------
extern "C" void kernel_launch(void* const* d_in, const int* in_sizes, int n_in,
                              void* d_out, int out_size, void* d_ws, size_t ws_size,
                              hipStream_t stream)
{
    const float* x    = (const float*)d_in[0];   // [4,4096,2048] f32
    const float* bias = (const float*)d_in[1];   // [64] f32
    const float* w    = (const float*)d_in[2];   // [64,2048] f32

    float* out     = (float*)d_out;
    float* partial = (float*)d_ws;

    const size_t bytesPerSlice = (size_t)T_TOTAL * NEXP * 4;   // 4 MiB

    if (ws_size >= 16 * bytesPerSlice) {
        router_gemm_kernel<16><<<dim3(64 * 16), dim3(256), 0, stream>>>(x, w, partial);
        router_topk_kernel<16><<<dim3(T_TOTAL / 64), dim3(1024), 0, stream>>>(
            partial, bias, out, out + (size_t)T_TOTAL * 8);
    } else {
        router_gemm_kernel<4><<<dim3(64 * 4), dim3(256), 0, stream>>>(x, w, partial);
        router_topk_kernel<4><<<dim3(T_TOTAL / 64), dim3(1024), 0, stream>>>(
            partial, bias, out, out + (size_t)T_TOTAL * 8);
    }
}